// Round 7
// baseline (230.308 us; speedup 1.0000x reference)
//
#include <hip/hip_runtime.h>
#include <hip/hip_bf16.h>

#define VOCAB 200000
#define EDIM  256
#define NTILES 12800            // 204800 rows / 16

typedef __attribute__((ext_vector_type(4))) float  f32x4;
typedef __attribute__((ext_vector_type(8))) __bf16 bf16x8;

typedef const __attribute__((address_space(1))) unsigned int* gas_u32p;
typedef __attribute__((address_space(3))) unsigned int* las_u32p;

__device__ __forceinline__ __bf16 f2bf(float f) {
    unsigned u = __builtin_bit_cast(unsigned, f);
    u += 0x7FFFu + ((u >> 16) & 1u);           // round-to-nearest-even
    unsigned short s = (unsigned short)(u >> 16);
    return __builtin_bit_cast(__bf16, s);
}

// Pack B into MFMA fragment order (verified round 1) + reset work counter.
// k = a*16 + b;  B[k][j] = core1[b, j, a], core1 is (16,256,16).
// bpk[(kk*16 + nt)*64 + lane] : lane l elem e = B[kk*32 + (l>>4)*8 + e][nt*16 + (l&15)]
__global__ void pack_b_kernel(const float* __restrict__ core1, bf16x8* __restrict__ bpk,
                              unsigned* __restrict__ counter) {
    if (blockIdx.x == 0 && threadIdx.x == 0) *counter = 0u;   // stream-ordered: runs before main kernel
    int t    = blockIdx.x * 256 + threadIdx.x;   // 0..8191
    int lane = t & 63;
    int nt   = (t >> 6) & 15;
    int kk   = t >> 10;
    int j     = nt * 16 + (lane & 15);
    int kbase = kk * 32 + ((lane >> 4) * 8);
    bf16x8 v;
#pragma unroll
    for (int e = 0; e < 8; ++e) {
        int k = kbase + e;
        int b = k & 15, a = k >> 4;
        v[e] = f2bf(core1[(b * 256 + j) * 16 + a]);
    }
    bpk[t] = v;
}

// 256 blocks x 1024 threads (16 waves), 1 block/CU (128 KB LDS = full B).
// ONE barrier (after B staging); then waves free-run on 16-row tiles pulled
// from a device-scope atomic counter. Per tile: idx -> 16-load A burst
// (sched_barrier pins the burst) -> cvt -> 128 MFMA from LDS -> stores.
// No steady-state barriers => wave phases stagger => HBM pipe stays full.
__global__ __launch_bounds__(1024, 4) void tr_embed_kernel(
        const int* __restrict__ x, const float* __restrict__ core0,
        const bf16x8* __restrict__ bpk, unsigned* __restrict__ counter,
        float* __restrict__ out) {
    __shared__ bf16x8 smem[8192];               // 128 KB: [kk 0..7][nt 0..15][lane 0..63]
    const int tid  = threadIdx.x;
    const int lane = tid & 63;
    const int wave = tid >> 6;                  // 0..15

    // ---- stage ALL of B into LDS (zero VGPR; L2-resident source) ----
#pragma unroll
    for (int i = 0; i < 8; ++i) {
        const bf16x8* src = bpk + i * 1024 + tid;
        __builtin_amdgcn_global_load_lds((gas_u32p)src,
                                         (las_u32p)(smem + i * 1024 + wave * 64), 16, 0, 0);
    }

    const int half = lane >> 4;                 // 0..3
    const int col  = lane & 15;
    const long KST = 2L * VOCAB * 16;           // floats per k-step (a advances by 2)

    __syncthreads();                            // only barrier: B resident

    for (;;) {
        int t = 0;
        if (lane == 0) t = (int)atomicAdd(counter, 1u);
        t = __builtin_amdgcn_readfirstlane(t);
        if (t >= NTILES) break;

        const int rowBase = t * 16;
        const int idx = x[rowBase + col];
        // A gather: k = a*16+b; k-step kk covers a = 2kk + (half>>1), b = (half&1)*8 + e
        const float* aptr = core0 + ((long)(half >> 1) * VOCAB + idx) * 16 + (half & 1) * 8;

        // burst: all 16 scattered dwordx4 in flight before any use
        f32x4 pa[8], pb[8];
#pragma unroll
        for (int k = 0; k < 8; ++k) {
            pa[k] = *(const f32x4*)(aptr + k * KST);
            pb[k] = *(const f32x4*)(aptr + k * KST + 4);
        }
        __builtin_amdgcn_sched_barrier(0);      // keep the burst a burst

        bf16x8 af[8];
#pragma unroll
        for (int k = 0; k < 8; ++k)
#pragma unroll
            for (int e = 0; e < 4; ++e) { af[k][e] = f2bf(pa[k][e]); af[k][e + 4] = f2bf(pb[k][e]); }

        f32x4 acc[16] = {};
#pragma unroll
        for (int kk = 0; kk < 8; ++kk) {
            const bf16x8* bs = smem + kk * 1024 + lane;
#pragma unroll
            for (int nt = 0; nt < 16; ++nt)
                acc[nt] = __builtin_amdgcn_mfma_f32_16x16x32_bf16(af[kk], bs[nt * 64], acc[nt], 0, 0, 0);
        }

        // C/D layout: col = lane&15, row = (lane>>4)*4 + reg (verified)
        float* obase = out + (long)rowBase * 256 + col;
#pragma unroll
        for (int nt = 0; nt < 16; ++nt)
#pragma unroll
            for (int e = 0; e < 4; ++e)
                obase[(half * 4 + e) * 256 + nt * 16] = acc[nt][e];
    }
}

extern "C" void kernel_launch(void* const* d_in, const int* in_sizes, int n_in,
                              void* d_out, int out_size, void* d_ws, size_t ws_size,
                              hipStream_t stream) {
    const int*   x     = (const int*)d_in[0];
    const float* core0 = (const float*)d_in[1];
    const float* core1 = (const float*)d_in[2];
    float* out = (float*)d_out;
    bf16x8*   bpk     = (bf16x8*)d_ws;                          // 128 KB scratch
    unsigned* counter = (unsigned*)((char*)d_ws + 131072);      // 4 B work counter

    pack_b_kernel<<<32, 256, 0, stream>>>(core1, bpk, counter);
    tr_embed_kernel<<<256, 1024, 0, stream>>>(x, core0, bpk, counter, out);
}

// Round 8
// 176.764 us; speedup vs baseline: 1.3029x; 1.3029x over previous
//
#include <hip/hip_runtime.h>
#include <hip/hip_bf16.h>

#define VOCAB 200000
#define EDIM  256

typedef __attribute__((ext_vector_type(4))) float  f32x4;
typedef __attribute__((ext_vector_type(8))) __bf16 bf16x8;

typedef const __attribute__((address_space(1))) unsigned int* gas_u32p;
typedef __attribute__((address_space(3))) unsigned int* las_u32p;

__device__ __forceinline__ __bf16 f2bf(float f) {
    unsigned u = __builtin_bit_cast(unsigned, f);
    u += 0x7FFFu + ((u >> 16) & 1u);           // round-to-nearest-even
    unsigned short s = (unsigned short)(u >> 16);
    return __builtin_bit_cast(__bf16, s);
}

// Pack B into MFMA fragment order (verified round 1).
// k = a*16 + b;  B[k][j] = core1[b, j, a], core1 is (16,256,16).
// bpk[(kk*16 + nt)*64 + lane] : lane l elem e = B[kk*32 + (l>>4)*8 + e][nt*16 + (l&15)]
__global__ void pack_b_kernel(const float* __restrict__ core1, bf16x8* __restrict__ bpk) {
    int t    = blockIdx.x * 256 + threadIdx.x;   // 0..8191
    int lane = t & 63;
    int nt   = (t >> 6) & 15;
    int kk   = t >> 10;
    int j     = nt * 16 + (lane & 15);
    int kbase = kk * 32 + ((lane >> 4) * 8);
    bf16x8 v;
#pragma unroll
    for (int e = 0; e < 8; ++e) {
        int k = kbase + e;
        int b = k & 15, a = k >> 4;
        v[e] = f2bf(core1[(b * 256 + j) * 16 + a]);
    }
    bpk[t] = v;
}

// Block = 256 thr (4 waves): 64 gathered rows x 128 cols.
// ALL scattered A reads go through global_load_lds (per-lane global src, zero
// VGPR): one instruction gathers one embedding row (64 lanes x 16 B). Source is
// XOR-pre-swizzled (chunk g = lane ^ (r&7)) so ds_read_b128 of A fragments is
// bank-conflict-free (same involution on the read side). One barrier (vmcnt(0)
// drain) syncs everything; 128 KB of loads in flight per CU hides HBM latency.
// XCD-pair swizzle (proven r4): colHalf partner's A-gather hits the XCD L2.
__global__ __launch_bounds__(256) void tr_embed_kernel(
        const int* __restrict__ x, const float* __restrict__ core0,
        const bf16x8* __restrict__ bpk, float* __restrict__ out) {
    __shared__ f32x4 smem4[8192];               // 128 KB: [0,64K)=B half, [64K,128K)=A (16K/wave)
    char* const base = (char*)smem4;
    const int tid  = threadIdx.x;
    const int lane = tid & 63;
    const int wave = tid >> 6;                  // 0..3

    // grid = 6400 = 8 XCDs * 800 slots; pair (rowTile, colHalf 0/1) adjacent on one XCD
    const int xcd  = blockIdx.x & 7;
    const int slot = blockIdx.x >> 3;           // 0..799
    const int rowTile = xcd * 400 + (slot >> 1);   // 0..3199
    const int colHalf = slot & 1;

    const int rowBase = rowTile * 64 + wave * 16;  // < 204800
    const int myidx = x[rowBase + (lane & 15)];    // lanes 0..15 hold rows 0..15

    // ---- stage B col-half: 64 rows of 1 KB, 16 insts/wave (L2-resident src) ----
    // B LDS row rb = kk*8 + ntl at byte rb*1024 + lane*16
#pragma unroll
    for (int i = 0; i < 16; ++i) {
        int rb  = wave * 16 + i;                // 0..63
        int kk  = rb >> 3, ntl = rb & 7;
        const bf16x8* src = bpk + (kk * 16 + colHalf * 8 + ntl) * 64 + lane;
        __builtin_amdgcn_global_load_lds((gas_u32p)src, (las_u32p)(base + rb * 1024), 16, 0, 0);
    }

    // ---- gather A: one inst per row; lane l fetches global chunk g = l ^ (r&7) ----
    // chunk g = floats k=4g..4g+3 of the row (k = a*16+b): a = g>>2, b-base = (g&3)*4
    char* const awave = base + 65536 + wave * 16384;
#pragma unroll
    for (int r = 0; r < 16; ++r) {
        int idxr = __builtin_amdgcn_readlane(myidx, r);
        int g = lane ^ (r & 7);
        const float* src = core0 + ((long)(g >> 2) * VOCAB + idxr) * 16 + (g & 3) * 4;
        __builtin_amdgcn_global_load_lds((gas_u32p)src, (las_u32p)(awave + r * 1024), 16, 0, 0);
    }

    __syncthreads();                            // vmcnt(0) drain: B + all A rows resident

    // ---- compute: 8 kk x 8 ntl MFMAs from LDS ----
    const int q = lane >> 4;                    // 0..3
    const int s = lane & 7;                     // = (lane&15)&7
    const char* ab = awave + (lane & 15) * 1024;
    f32x4 acc[8] = {};
#pragma unroll
    for (int kk = 0; kk < 8; ++kk) {
        int c0 = kk * 8 + q * 2;
        f32x4 lo = *(const f32x4*)(ab + ((c0 ^ s) << 4));          // k = kk*32+q*8 .. +3
        f32x4 hi = *(const f32x4*)(ab + (((c0 + 1) ^ s) << 4));    // k = .. +4 .. +7
        bf16x8 af;
#pragma unroll
        for (int e = 0; e < 4; ++e) { af[e] = f2bf(lo[e]); af[e + 4] = f2bf(hi[e]); }

        const char* bb = base + kk * 8192 + lane * 16;
#pragma unroll
        for (int ntl = 0; ntl < 8; ++ntl) {
            bf16x8 bfr = *(const bf16x8*)(bb + ntl * 1024);
            acc[ntl] = __builtin_amdgcn_mfma_f32_16x16x32_bf16(af, bfr, acc[ntl], 0, 0, 0);
        }
    }

    // C/D layout: col = lane&15, row = q*4 + reg (verified)
    float* obase = out + (long)rowBase * 256 + colHalf * 128 + (lane & 15);
#pragma unroll
    for (int ntl = 0; ntl < 8; ++ntl)
#pragma unroll
        for (int e = 0; e < 4; ++e)
            obase[(q * 4 + e) * 256 + ntl * 16] = acc[ntl][e];
}

extern "C" void kernel_launch(void* const* d_in, const int* in_sizes, int n_in,
                              void* d_out, int out_size, void* d_ws, size_t ws_size,
                              hipStream_t stream) {
    const int*   x     = (const int*)d_in[0];
    const float* core0 = (const float*)d_in[1];
    const float* core1 = (const float*)d_in[2];
    float* out = (float*)d_out;
    bf16x8* bpk = (bf16x8*)d_ws;                // 128 KB scratch

    pack_b_kernel<<<32, 256, 0, stream>>>(core1, bpk);
    // 3200 rowTiles(64 rows) * 2 col-halves = 6400 blocks = 8 XCDs * 800 slots
    tr_embed_kernel<<<6400, 256, 0, stream>>>(x, core0, bpk, out);
}

// Round 9
// 115.810 us; speedup vs baseline: 1.9887x; 1.5263x over previous
//
#include <hip/hip_runtime.h>
#include <hip/hip_bf16.h>

#define VOCAB 200000
#define EDIM  256
#define NTILES 12800            // 204800 rows / 16
#define GRID   512              // persistent blocks, 2 per CU
#define ITERS  25               // NTILES / GRID

typedef __attribute__((ext_vector_type(4))) float  f32x4;
typedef __attribute__((ext_vector_type(4))) int    i32x4;
typedef __attribute__((ext_vector_type(8))) __bf16 bf16x8;

typedef const __attribute__((address_space(1))) unsigned int* gas_u32p;
typedef __attribute__((address_space(3))) unsigned int* las_u32p;

__device__ __forceinline__ __bf16 f2bf(float f) {
    unsigned u = __builtin_bit_cast(unsigned, f);
    u += 0x7FFFu + ((u >> 16) & 1u);           // round-to-nearest-even
    unsigned short s = (unsigned short)(u >> 16);
    return __builtin_bit_cast(__bf16, s);
}

// Pack B into MFMA fragment order (verified round 1).
// k = a*16 + b;  B[k][j] = core1[b, j, a], core1 is (16,256,16).
// bpk[(kk*16 + nt)*64 + lane] : lane l elem e = B[kk*32 + (l>>4)*8 + e][nt*16 + (l&15)]
__global__ void pack_b_kernel(const float* __restrict__ core1, bf16x8* __restrict__ bpk) {
    int t    = blockIdx.x * 256 + threadIdx.x;   // 0..8191
    int lane = t & 63;
    int nt   = (t >> 6) & 15;
    int kk   = t >> 10;
    int j     = nt * 16 + (lane & 15);
    int kbase = kk * 32 + ((lane >> 4) * 8);
    bf16x8 v;
#pragma unroll
    for (int e = 0; e < 8; ++e) {
        int k = kbase + e;
        int b = k & 15, a = k >> 4;
        v[e] = f2bf(core1[(b * 256 + j) * 16 + a]);
    }
    bpk[t] = v;
}

// Issue the A-gather for one k-slab (kk) of a 16-row tile into LDS buffer abuf.
// Per-lane global src (the gather); wave-uniform LDS dest (+lane*16 linear).
// Lane l fetches chunk c = kk*8 + (l>>4)*2 + h of row idx_{l&15}; chunk c =
// floats 4c..4c+3 of the row = core0[a = c>>2][idx][b = (c&3)*4 ..+3].
// LDS image: addr kk*2048 + h*1024 + lane*16  -> compute reads are contiguous.
__device__ __forceinline__ void issue_gather(const float* __restrict__ core0, int idx,
                                             int kk, char* abuf, int lane) {
    const int q = lane >> 4;
#pragma unroll
    for (int h = 0; h < 2; ++h) {
        int c = kk * 8 + q * 2 + h;
        const float* src = core0 + ((long)(c >> 2) * VOCAB + idx) * 16 + (c & 3) * 4;
        __builtin_amdgcn_global_load_lds((gas_u32p)src,
                                         (las_u32p)(abuf + kk * 2048 + h * 1024), 16, 0, 0);
    }
}

// 512 persistent blocks (2/CU) x 512 thr (8 waves). Each block: 25 tiles of
// 16 rows x 256 cols. B panel lives in REGISTERS (wave w owns cols nt=2w,2w+1:
// 16 frags = 64 VGPR, loaded once). LDS = only double-buffered A tile (2x16KB)
// filled by zero-VGPR global_load_lds gathers. Counted vmcnt(8) + raw barrier
// per tile keeps stores in flight and overlaps tile t+1's gather with tile t's
// compute. Idx prefetched 2 tiles deep.
__global__ __launch_bounds__(512, 4) void tr_embed_kernel(
        const int* __restrict__ x, const float* __restrict__ core0,
        const bf16x8* __restrict__ bpk, float* __restrict__ out) {
    __shared__ f32x4 smem4[2048];               // 32 KB: two 16 KB A buffers
    char* const lds = (char*)smem4;
    const int tid  = threadIdx.x;
    const int lane = tid & 63;
    const int wave = tid >> 6;                  // 0..7
    const int r    = lane & 15;
    const int q    = lane >> 4;

    // ---- B panel -> registers: wave w owns nt = 2w, 2w+1 (once per block) ----
    bf16x8 B0[8], B1[8];
#pragma unroll
    for (int kk = 0; kk < 8; ++kk) {
        B0[kk] = bpk[(kk * 16 + 2 * wave)     * 64 + lane];
        B1[kk] = bpk[(kk * 16 + 2 * wave + 1) * 64 + lane];
    }

    const int b0 = blockIdx.x;                  // first tile of this block
    char* bufA = lds;
    char* bufB = lds + 16384;

    // prologue: gather tile 0 into bufA; prefetch idx for tile 1
    int idxC = x[b0 * 16 + r];
    issue_gather(core0, idxC, wave, bufA, lane);
    int idxN = x[(b0 + GRID) * 16 + r];         // b0+GRID < NTILES always
    asm volatile("s_waitcnt vmcnt(0)" ::: "memory");
    __builtin_amdgcn_s_barrier();

    for (int i = 0; i < ITERS; ++i) {
        const int t = b0 + i * GRID;
        char* cur = (i & 1) ? bufB : bufA;
        char* nxt = (i & 1) ? bufA : bufB;

        // issue next tile's gathers (2 insts/wave) + idx prefetch 2 deep
        if (i + 1 < ITERS) {
            issue_gather(core0, idxN, wave, nxt, lane);
            if (i + 2 < ITERS) idxN = x[(t + 2 * GRID) * 16 + r];
        }
        __builtin_amdgcn_sched_barrier(0);      // pin the gather burst up here

        // ---- compute 16 rows x 32 cols per wave from LDS A + reg B ----
        f32x4 acc0 = {}, acc1 = {};
#pragma unroll
        for (int kk = 0; kk < 8; ++kk) {
            f32x4 lo = *(const f32x4*)(cur + kk * 2048 +        lane * 16);
            f32x4 hi = *(const f32x4*)(cur + kk * 2048 + 1024 + lane * 16);
            int p0, p1, p2, p3;                 // RNE packed f32->bf16 (T12 recipe)
            asm("v_cvt_pk_bf16_f32 %0, %1, %2" : "=v"(p0) : "v"(lo[0]), "v"(lo[1]));
            asm("v_cvt_pk_bf16_f32 %0, %1, %2" : "=v"(p1) : "v"(lo[2]), "v"(lo[3]));
            asm("v_cvt_pk_bf16_f32 %0, %1, %2" : "=v"(p2) : "v"(hi[0]), "v"(hi[1]));
            asm("v_cvt_pk_bf16_f32 %0, %1, %2" : "=v"(p3) : "v"(hi[2]), "v"(hi[3]));
            i32x4 pk = { p0, p1, p2, p3 };
            bf16x8 af = __builtin_bit_cast(bf16x8, pk);
            acc0 = __builtin_amdgcn_mfma_f32_16x16x32_bf16(af, B0[kk], acc0, 0, 0, 0);
            acc1 = __builtin_amdgcn_mfma_f32_16x16x32_bf16(af, B1[kk], acc1, 0, 0, 0);
        }

        // C/D layout: col = lane&15, row = q*4 + e (verified)
        float* ob = out + (long)t * 16 * 256 + (q * 4) * 256 + 2 * wave * 16 + r;
#pragma unroll
        for (int e = 0; e < 4; ++e) {
            ob[e * 256]      = acc0[e];
            ob[e * 256 + 16] = acc1[e];
        }

        // counted drain: 8 stores stay in flight; gathers+idx (issued before
        // them) are forced complete. Raw barrier (no full vmcnt(0) drain).
        asm volatile("s_waitcnt vmcnt(8)" ::: "memory");
        __builtin_amdgcn_s_barrier();
    }
}

extern "C" void kernel_launch(void* const* d_in, const int* in_sizes, int n_in,
                              void* d_out, int out_size, void* d_ws, size_t ws_size,
                              hipStream_t stream) {
    const int*   x     = (const int*)d_in[0];
    const float* core0 = (const float*)d_in[1];
    const float* core1 = (const float*)d_in[2];
    float* out = (float*)d_out;
    bf16x8* bpk = (bf16x8*)d_ws;                // 128 KB scratch

    pack_b_kernel<<<32, 256, 0, stream>>>(core1, bpk);
    tr_embed_kernel<<<GRID, 512, 0, stream>>>(x, core0, bpk, out);
}